// Round 6
// baseline (549.102 us; speedup 1.0000x reference)
//
#include <hip/hip_runtime.h>
#include <hip/hip_bf16.h>

#define DIN 256
#define DOUT 128

using short8  = __attribute__((ext_vector_type(8))) short;
using floatx4 = __attribute__((ext_vector_type(4))) float;

__device__ __forceinline__ unsigned short f2bf(float f) {
    union { float f; unsigned u; } x; x.f = f;
    unsigned u = x.u;
    unsigned r = u + 0x7fffu + ((u >> 16) & 1u);   // round-to-nearest-even
    return (unsigned short)(r >> 16);
}

// Bfrag in MFMA-fragment order, lane-major (verified R2/R4/R5):
//   Bfrag[((ct*8 + ks)*64 + lane)*8 + j] = bf16(W0[(ks*32 + (lane>>4)*8 + j)][ct*16 + (lane&15)])
__global__ void w0_pack_kernel(const float* __restrict__ W0,
                               unsigned short* __restrict__ Bfrag) {
    int e = blockIdx.x * blockDim.x + threadIdx.x;   // 32768 elements
    int j  = e & 7;
    int l  = (e >> 3) & 63;
    int ks = (e >> 9) & 7;
    int ct = e >> 12;
    int k = ks * 32 + (l >> 4) * 8 + j;
    int c = ct * 16 + (l & 15);
    Bfrag[e] = f2bf(W0[k * DOUT + c]);
}

// 512 threads = 8 waves; each wave owns 16 nodes x all 128 cols per tile,
// and loops over T tiles with next-tile gathers always in flight.
// One barrier total (B-stage); waves are independent pipelined streams.
__global__ __launch_bounds__(512, 2) void fused_embed_kernel(
    const float* __restrict__ feat0,
    const float* __restrict__ emb_table,
    const unsigned short* __restrict__ Bfrag,
    const int* __restrict__ node_ids,
    const int* __restrict__ node_tids,
    const int* __restrict__ type_ids,
    float* __restrict__ out,
    int n, int T)
{
    __shared__ short8 sB[4096];   // [ct][ks][lane] = 64 KB

    const int t    = threadIdx.x;
    const int w    = t >> 6;      // wave 0..7
    const int l    = t & 63;
    const int lr   = l & 15;      // A row in wave tile / D col
    const int kg   = l >> 4;      // k-group / D row group
    const int crow = l >> 2;      // copy path: row 0..15
    const int csub = l & 3;       // copy path: 4 lanes per row

    // ---- stage B (reg-staged coalesced copy) ----
    {
        const short8* src = reinterpret_cast<const short8*>(Bfrag);
        short8 tmp[8];
        #pragma unroll
        for (int j = 0; j < 8; ++j) tmp[j] = src[t + j * 512];
        #pragma unroll
        for (int j = 0; j < 8; ++j) sB[t + j * 512] = tmp[j];
    }

    const long long wbase = ((long long)blockIdx.x * 8 + w) * ((long long)T * 16);

    float4 av[16];
    float4 ev[8];

    auto loadIdx = [&](int tt, int& tid, int& gt, int& gn) {
        tid = -1; gt = 0; gn = 0;
        if (tt < T) {
            const long long row = wbase + (long long)tt * 16 + lr;
            if (row < n) { tid = node_tids[row]; gt = type_ids[row]; gn = node_ids[row]; }
        }
    };
    auto issueA = [&](int tid, int gt) {
        const int gts = (tid == 0) ? gt : 0;         // featureless -> row 0 (L1 dedup)
        const float4* arow = reinterpret_cast<const float4*>(
            feat0 + (long long)gts * DIN) + kg * 2;
        #pragma unroll
        for (int ks = 0; ks < 8; ++ks) {
            av[2 * ks]     = arow[ks * 8];
            av[2 * ks + 1] = arow[ks * 8 + 1];
        }
    };
    auto issueE = [&](int tid, int gn_self) {
        const int t_c  = __shfl(tid, crow);
        const int gn_c = __shfl(gn_self, crow);
        const int gns  = (t_c == 1) ? gn_c : 0;
        const float4* esrc = reinterpret_cast<const float4*>(
            emb_table + (long long)gns * DOUT);
        #pragma unroll
        for (int j = 0; j < 8; ++j) ev[j] = esrc[csub + j * 4];
    };

    // ---- prologue: idx for tiles 0,1; gathers for tile 0 ----
    int tidC, gtC, gnC, tidN, gtN, gnN;
    loadIdx(0, tidC, gtC, gnC);
    loadIdx(1, tidN, gtN, gnN);
    issueA(tidC, gtC);
    issueE(tidC, gnC);

    __syncthreads();   // sB ready

    // ---- pipelined tile loop: no barriers, loads always in flight ----
    for (int tt = 0; tt < T; ++tt) {
        const long long nodebase = wbase + (long long)tt * 16;
        const int tidS = tidC;

        // 1. convert current A (drains its vmcnt)
        short8 afs[8];
        #pragma unroll
        for (int ks = 0; ks < 8; ++ks) {
            const float4 a0 = av[2 * ks];
            const float4 a1 = av[2 * ks + 1];
            short8 af;
            af[0] = (short)f2bf(a0.x); af[1] = (short)f2bf(a0.y);
            af[2] = (short)f2bf(a0.z); af[3] = (short)f2bf(a0.w);
            af[4] = (short)f2bf(a1.x); af[5] = (short)f2bf(a1.y);
            af[6] = (short)f2bf(a1.z); af[7] = (short)f2bf(a1.w);
            afs[ks] = af;
        }

        // 2. store current emb rows (loads landed an iter ago)
        {
            const int t_c = __shfl(tidS, crow);
            const long long cnode = nodebase + crow;
            if (t_c == 1 && cnode < n) {
                float4* dst = reinterpret_cast<float4*>(out + cnode * DOUT);
                #pragma unroll
                for (int j = 0; j < 8; ++j) dst[csub + j * 4] = ev[j];
            }
        }

        // 3. issue next tile's gathers (in flight under MFMA below)
        if (tt + 1 < T) {
            issueA(tidN, gtN);
            issueE(tidN, gnN);
        }

        // 4. prefetch idx for tile tt+2
        int tid2, gt2, gn2;
        loadIdx(tt + 2, tid2, gt2, gn2);

        // 5. MFMA
        floatx4 acc[8];
        #pragma unroll
        for (int ct = 0; ct < 8; ++ct) acc[ct] = (floatx4){0.f, 0.f, 0.f, 0.f};
        #pragma unroll
        for (int ks = 0; ks < 8; ++ks) {
            #pragma unroll
            for (int ct = 0; ct < 8; ++ct)
                acc[ct] = __builtin_amdgcn_mfma_f32_16x16x32_bf16(
                    afs[ks], sB[(ct * 8 + ks) * 64 + l], acc[ct], 0, 0, 0);
        }

        // 6. store projected rows (D: row = kg*4+r, col = ct*16+lr)
        #pragma unroll
        for (int r = 0; r < 4; ++r) {
            const int row = kg * 4 + r;
            const int t_r = __shfl(tidS, row);
            const long long node = nodebase + row;
            if (t_r == 0 && node < n) {
                float* orow = out + node * DOUT;
                #pragma unroll
                for (int ct = 0; ct < 8; ++ct)
                    orow[ct * 16 + lr] = acc[ct][r];
            }
        }

        // 7. rotate index registers
        tidC = tidN; gtC = gtN; gnC = gnN;
        tidN = tid2; gtN = gt2; gnN = gn2;
    }
}

extern "C" void kernel_launch(void* const* d_in, const int* in_sizes, int n_in,
                              void* d_out, int out_size, void* d_ws, size_t ws_size,
                              hipStream_t stream) {
    const float* feat0      = (const float*)d_in[0];
    const float* W0         = (const float*)d_in[1];
    const float* emb_table  = (const float*)d_in[2];
    const int*   node_ids   = (const int*)d_in[3];
    const int*   node_tids  = (const int*)d_in[4];
    const int*   type_ids   = (const int*)d_in[5];
    float*       out        = (float*)d_out;
    const int n = in_sizes[3];                      // N = 500000

    unsigned short* Bfrag = (unsigned short*)d_ws;  // 64 KB in workspace

    hipLaunchKernelGGL(w0_pack_kernel, dim3((DIN * DOUT) / 256), dim3(256),
                       0, stream, W0, Bfrag);

    const int T = 8;                                 // tiles per wave
    const int wtiles = (n + 15) / 16;                // 31250
    const int grid = (wtiles + 8 * T - 1) / (8 * T); // 489
    hipLaunchKernelGGL(fused_embed_kernel, dim3(grid), dim3(512), 0, stream,
                       feat0, emb_table, Bfrag, node_ids, node_tids, type_ids,
                       out, n, T);
}

// Round 7
// 156.348 us; speedup vs baseline: 3.5121x; 3.5121x over previous
//
#include <hip/hip_runtime.h>
#include <hip/hip_bf16.h>

#define DIN 256
#define DOUT 128

using short8  = __attribute__((ext_vector_type(8))) short;
using floatx4 = __attribute__((ext_vector_type(4))) float;

__device__ __forceinline__ unsigned short f2bf(float f) {
    union { float f; unsigned u; } x; x.f = f;
    unsigned u = x.u;
    unsigned r = u + 0x7fffu + ((u >> 16) & 1u);   // round-to-nearest-even
    return (unsigned short)(r >> 16);
}

// 2 floats -> packed bf16x2; compiler emits v_cvt_pk_bf16_f32
__device__ __forceinline__ unsigned cvt2(float x, float y) {
    union { __hip_bfloat162 h2; unsigned u; } c;
    c.h2 = __float22bfloat162_rn(float2{x, y});
    return c.u;
}

// Bfrag in MFMA-fragment order, lane-major (verified R2/R4/R5):
//   Bfrag[((ct*8 + ks)*64 + lane)*8 + j] = bf16(W0[(ks*32 + (lane>>4)*8 + j)][ct*16 + (lane&15)])
__global__ void w0_pack_kernel(const float* __restrict__ W0,
                               unsigned short* __restrict__ Bfrag) {
    int e = blockIdx.x * blockDim.x + threadIdx.x;   // 32768 elements
    int j  = e & 7;
    int l  = (e >> 3) & 63;
    int ks = (e >> 9) & 7;
    int ct = e >> 12;
    int k = ks * 32 + (l >> 4) * 8 + j;
    int c = ct * 16 + (l & 15);
    Bfrag[e] = f2bf(W0[k * DOUT + c]);
}

// 512 threads = 8 waves; each wave owns 16 nodes x all 128 cols.
// One barrier per block (B-stage). VGPR capped at 128 so TWO blocks
// co-reside per CU: one block's load-latency phase overlaps the other's
// convert+MFMA+store phase.
__global__ __launch_bounds__(512, 4) void fused_embed_kernel(
    const float* __restrict__ feat0,
    const float* __restrict__ emb_table,
    const unsigned short* __restrict__ Bfrag,
    const int* __restrict__ node_ids,
    const int* __restrict__ node_tids,
    const int* __restrict__ type_ids,
    float* __restrict__ out,
    int n)
{
    __shared__ short8 sB[4096];   // [ct][ks][lane] = 64 KB

    const int t  = threadIdx.x;
    const int w  = t >> 6;        // wave 0..7
    const int l  = t & 63;
    const int lr = l & 15;        // A row in wave tile / D col
    const int kg = l >> 4;        // k-group / D row group

    // ---- 1. indices first (earliest issue; 4x redundant across kg) ----
    const long long nodebase = (long long)blockIdx.x * 128 + w * 16;
    const long long myrow = nodebase + lr;
    int tid = 1, gt = 0, gn = 0;
    if (myrow < n) {
        tid = node_tids[myrow];
        gt  = type_ids[myrow];
        gn  = node_ids[myrow];
    }

    // ---- 2. stage B (reg-staged coalesced copy) ----
    {
        const short8* src = reinterpret_cast<const short8*>(Bfrag);
        short8 tmp[8];
        #pragma unroll
        for (int j = 0; j < 8; ++j) tmp[j] = src[t + j * 512];
        #pragma unroll
        for (int j = 0; j < 8; ++j) sB[t + j * 512] = tmp[j];
    }

    // ---- 3. the ONLY barrier ----
    __syncthreads();

    // ---- 4. hoist 16 A-loads; featureless lanes hit row 0 (L1 dedup) ----
    const int gts = (tid == 0) ? gt : 0;
    const float4* arow = reinterpret_cast<const float4*>(
        feat0 + (long long)gts * DIN) + kg * 2;
    float4 av[16];
    #pragma unroll
    for (int ks = 0; ks < 8; ++ks) {
        av[2 * ks]     = arow[ks * 8];
        av[2 * ks + 1] = arow[ks * 8 + 1];
    }

    // ---- 5. emb-copy loads in flight too (4 lanes per row) ----
    const int crow = l >> 2;
    const int csub = l & 3;
    const int t_c  = __shfl(tid, crow);
    const int gn_c = __shfl(gn, crow);
    const long long cnode = nodebase + crow;
    const bool copyrow = (t_c == 1) && (cnode < n);
    const int  gns = copyrow ? gn_c : 0;
    const float4* esrc = reinterpret_cast<const float4*>(
        emb_table + (long long)gns * DOUT);
    float4 ev[8];
    #pragma unroll
    for (int j = 0; j < 8; ++j) ev[j] = esrc[csub + j * 4];

    // ---- 6. convert (v_cvt_pk_bf16_f32) + MFMA ----
    floatx4 acc[8];
    #pragma unroll
    for (int ct = 0; ct < 8; ++ct) acc[ct] = (floatx4){0.f, 0.f, 0.f, 0.f};
    #pragma unroll
    for (int ks = 0; ks < 8; ++ks) {
        const float4 a0 = av[2 * ks];
        const float4 a1 = av[2 * ks + 1];
        union { short8 s; unsigned u[4]; } af;
        af.u[0] = cvt2(a0.x, a0.y);
        af.u[1] = cvt2(a0.z, a0.w);
        af.u[2] = cvt2(a1.x, a1.y);
        af.u[3] = cvt2(a1.z, a1.w);
        #pragma unroll
        for (int ct = 0; ct < 8; ++ct)
            acc[ct] = __builtin_amdgcn_mfma_f32_16x16x32_bf16(
                af.s, sB[(ct * 8 + ks) * 64 + l], acc[ct], 0, 0, 0);
    }

    // ---- 7. store projected rows (D: row = kg*4+r, col = ct*16+lr) ----
    #pragma unroll
    for (int r = 0; r < 4; ++r) {
        const int row = kg * 4 + r;
        const int t_r = __shfl(tid, row);
        const long long node = nodebase + row;
        if (t_r == 0 && node < n) {
            float* orow = out + node * DOUT;
            #pragma unroll
            for (int ct = 0; ct < 8; ++ct)
                orow[ct * 16 + lr] = acc[ct][r];
        }
    }

    // ---- 8. featureless-row stores (loads long since landed) ----
    if (copyrow) {
        float4* dst = reinterpret_cast<float4*>(out + cnode * DOUT);
        #pragma unroll
        for (int j = 0; j < 8; ++j) dst[csub + j * 4] = ev[j];
    }
}

extern "C" void kernel_launch(void* const* d_in, const int* in_sizes, int n_in,
                              void* d_out, int out_size, void* d_ws, size_t ws_size,
                              hipStream_t stream) {
    const float* feat0      = (const float*)d_in[0];
    const float* W0         = (const float*)d_in[1];
    const float* emb_table  = (const float*)d_in[2];
    const int*   node_ids   = (const int*)d_in[3];
    const int*   node_tids  = (const int*)d_in[4];
    const int*   type_ids   = (const int*)d_in[5];
    float*       out        = (float*)d_out;
    const int n = in_sizes[3];                      // N = 500000

    unsigned short* Bfrag = (unsigned short*)d_ws;  // 64 KB in workspace

    hipLaunchKernelGGL(w0_pack_kernel, dim3((DIN * DOUT) / 256), dim3(256),
                       0, stream, W0, Bfrag);

    const int grid = (n + 127) / 128;               // 128 nodes per block
    hipLaunchKernelGGL(fused_embed_kernel, dim3(grid), dim3(512), 0, stream,
                       feat0, emb_table, Bfrag, node_ids, node_tids, type_ids,
                       out, n);
}